// Round 4
// baseline (405.145 us; speedup 1.0000x reference)
//
#include <hip/hip_runtime.h>
#include <cstdint>

typedef __attribute__((ext_vector_type(8))) short short8;
typedef __attribute__((ext_vector_type(4))) float f32x4;
typedef __attribute__((ext_vector_type(2))) float f32x2;

constexpr int NB   = 8;
constexpr int L    = 4096;
constexpr int CH   = 512;     // model dim == E_IN
constexpr int DD   = 64;
constexpr int NE   = 131072;
constexpr int M_ROWS = NB * L;  // 32768

__device__ __forceinline__ unsigned short f2bf(float f) {
    unsigned int x; __builtin_memcpy(&x, &f, 4);
    x += 0x7fffu + ((x >> 16) & 1u);
    return (unsigned short)(x >> 16);
}
__device__ __forceinline__ float u2f(unsigned int x) {
    float f; __builtin_memcpy(&f, &x, 4); return f;
}
// 2x f32 -> packed bf16 dword (RNE), single HW instr (verified gfx950)
__device__ __forceinline__ unsigned int cvt_pk_bf16(float a, float b) {
    unsigned int r;
    asm("v_cvt_pk_bf16_f32 %0, %1, %2" : "=v"(r) : "v"(a), "v"(b));
    return r;
}

// ---------------- f32 -> bf16 weight convert (2 MB total, tiny) ----------------
__global__ __launch_bounds__(256)
void cvtw_k(const float* __restrict__ s0, const float* __restrict__ s1,
            const float* __restrict__ s2, const float* __restrict__ s3,
            unsigned short* __restrict__ dst) {
    const float* s = (blockIdx.y == 0) ? s0 : (blockIdx.y == 1) ? s1
                   : (blockIdx.y == 2) ? s2 : s3;
    unsigned short* d = dst + (size_t)blockIdx.y * (CH * CH);
    const int i = blockIdx.x * 256 + threadIdx.x;
    const float4 a = ((const float4*)s)[i * 2];
    const float4 b = ((const float4*)s)[i * 2 + 1];
    unsigned short us[8];
    us[0] = f2bf(a.x); us[1] = f2bf(a.y); us[2] = f2bf(a.z); us[3] = f2bf(a.w);
    us[4] = f2bf(b.x); us[5] = f2bf(b.y); us[6] = f2bf(b.z); us[7] = f2bf(b.w);
    ((short8*)d)[i] = *(short8*)us;
}

// ---------------- B^T GEMM: C[m][n] = sum_k A[m][k]*B[n][k] + bias[n]
// M=32768, N=512, K=512. 128x128 tile, BK=64, 256 thr (4 waves 2x2).
// A_F32: A is f32 in HBM, reg-staged with fused v_cvt_pk_bf16_f32 (LDS stride 72,
//        16B-aligned b128 writes, 4-step bank spread).
// else:  A is bf16, staged via global_load_lds width-16 (linear LDS, stride 64).
// B always bf16 via global_load_lds. XCD-swizzled block id.
template <bool A_F32, bool OUT_F32>
__global__ __launch_bounds__(256)
void gemm_bf(const void* __restrict__ Ap, const unsigned short* __restrict__ B,
             const float* __restrict__ bias, void* __restrict__ Cp)
{
    constexpr int ASTR = A_F32 ? 72 : 64;
    __shared__ unsigned short As[128 * ASTR];
    __shared__ unsigned short Bs[128 * 64];
    const int bid = blockIdx.x;                     // 1024 blocks
    const int swz = (bid & 7) * 128 + (bid >> 3);   // bijective XCD swizzle
    const int row0 = (swz >> 2) * 128;
    const int col0 = (swz & 3) * 128;
    const int t = threadIdx.x, lane = t & 63, wid = t >> 6;
    const int wm = (wid >> 1) * 64, wn = (wid & 1) * 64;
    const int fr = lane & 15, fkb = (lane >> 4) * 8;
    const int srow = lane >> 3;          // staging row within 8-row chunk
    const int scol = (lane & 7) * 8;     // staging k-elem offset

    f32x4 acc[4][4] = {};

    for (int k0 = 0; k0 < CH; k0 += 64) {
        if constexpr (A_F32) {
            // reg-staged A: 32 f32/thread -> 16 cvt_pk -> 4x b128 LDS writes
            const int r = t >> 1, ch = (t & 1) * 32;
            const float4* ap = (const float4*)((const float*)Ap + (size_t)(row0 + r) * CH + k0 + ch);
            unsigned int pk[16];
#pragma unroll
            for (int q = 0; q < 8; q++) {
                const float4 x = ap[q];
                pk[2 * q]     = cvt_pk_bf16(x.x, x.y);
                pk[2 * q + 1] = cvt_pk_bf16(x.z, x.w);
            }
#pragma unroll
            for (int q = 0; q < 4; q++)
                *(uint4*)&As[r * ASTR + ch + q * 8] = *(uint4*)&pk[q * 4];
        } else {
#pragma unroll
            for (int q = 0; q < 4; q++) {
                const int r = wid * 32 + q * 8;
                __builtin_amdgcn_global_load_lds(
                    (const __attribute__((address_space(1))) unsigned int*)
                        ((const unsigned short*)Ap + (size_t)(row0 + r + srow) * CH + k0 + scol),
                    (__attribute__((address_space(3))) unsigned int*)(As + r * 64),
                    16, 0, 0);
            }
        }
#pragma unroll
        for (int q = 0; q < 4; q++) {
            const int r = wid * 32 + q * 8;
            __builtin_amdgcn_global_load_lds(
                (const __attribute__((address_space(1))) unsigned int*)
                    (B + (size_t)(col0 + r + srow) * CH + k0 + scol),
                (__attribute__((address_space(3))) unsigned int*)(Bs + r * 64),
                16, 0, 0);
        }
        __syncthreads();
#pragma unroll
        for (int kk = 0; kk < 2; kk++) {
            short8 afr[4], bfr[4];
#pragma unroll
            for (int f = 0; f < 4; f++)
                afr[f] = *(const short8*)&As[(wm + f * 16 + fr) * ASTR + kk * 32 + fkb];
#pragma unroll
            for (int f = 0; f < 4; f++)
                bfr[f] = *(const short8*)&Bs[(wn + f * 16 + fr) * 64 + kk * 32 + fkb];
#pragma unroll
            for (int fm = 0; fm < 4; fm++)
#pragma unroll
                for (int fn = 0; fn < 4; fn++)
                    acc[fm][fn] = __builtin_amdgcn_mfma_f32_16x16x32_bf16(
                        afr[fm], bfr[fn], acc[fm][fn], 0, 0, 0);
        }
        __syncthreads();
    }

    const int rsub = (lane >> 4) * 4;
#pragma unroll
    for (int fn = 0; fn < 4; fn++) {
        const int gc = col0 + wn + fn * 16 + fr;
        const float bv = bias[gc];
#pragma unroll
        for (int fm = 0; fm < 4; fm++) {
            const int gr = row0 + wm + fm * 16 + rsub;
#pragma unroll
            for (int j = 0; j < 4; j++) {
                float v = acc[fm][fn][j] + bv;
                if constexpr (OUT_F32)
                    ((float*)Cp)[(size_t)(gr + j) * CH + gc] = v;
                else
                    ((unsigned short*)Cp)[(size_t)(gr + j) * CH + gc] = f2bf(v);
            }
        }
    }
}

// ---------------- CSR build ----------------
__global__ void zero_k(int* cnt, int* fill) {
    int i = blockIdx.x * blockDim.x + threadIdx.x;
    if (i < L) { cnt[i] = 0; fill[i] = 0; }
}
__global__ void count_k(const int* __restrict__ adj, int* __restrict__ cnt) {
    int e = blockIdx.x * blockDim.x + threadIdx.x;
    if (e < NE) atomicAdd(&cnt[adj[e]], 1);
}
__global__ void scan_k(const int* __restrict__ cnt, int* __restrict__ rowptr) {
    const int lane = threadIdx.x;      // 64 threads, 1 wave
    const int base = lane * 64;
    int s = 0;
    for (int t2 = 0; t2 < 64; t2++) s += cnt[base + t2];
    int incl = s;
    for (int off = 1; off < 64; off <<= 1) {
        int v = __shfl_up(incl, off);
        if (lane >= off) incl += v;
    }
    int run = incl - s;   // exclusive prefix
    for (int t2 = 0; t2 < 64; t2++) { rowptr[base + t2] = run; run += cnt[base + t2]; }
    if (lane == 63) rowptr[L] = run;
}
__global__ void scatter_k(const int* __restrict__ adj, const int* __restrict__ rowptr,
                          int* __restrict__ fill, int* __restrict__ ecol) {
    int e = blockIdx.x * blockDim.x + threadIdx.x;
    if (e < NE) {
        int rr = adj[e];
        int pos = rowptr[rr] + atomicAdd(&fill[rr], 1);
        ecol[pos] = adj[NE + e];
    }
}

// ---------------- fused edge-softmax + SPMM ----------------
// block = (i, n, hg): 256 threads = 4 waves, wave w handles head hg*4+w.
// XCD pinning: n = bid & 7 -> per-XCD live K/V slice = 4 MB = one L2 (round-3 win:
// FETCH 614->136 MB). Wave: 8 groups x 8 lanes, one edge/group/iter, 16B K/V loads.
// No-max softmax (scores ~N(0,1), exp2-domain, scale folded into Q).
// f32x2 packed math (v_pk_fma_f32) for dot + accumulate.
__global__ __launch_bounds__(256)
void attn_k(const unsigned short* __restrict__ qb, const unsigned short* __restrict__ kb,
            const unsigned short* __restrict__ vb, const int* __restrict__ rowptr,
            const int* __restrict__ ecol, unsigned short* __restrict__ agg)
{
    __shared__ float part[4 * 8 * 68];   // [wave][grp][68]: 16B-aligned rows, stride-1 reads
    const int bid = blockIdx.x;
    const int n   = bid & 7;
    const int rem = bid >> 3;
    const int hg  = rem >> 12;          // 0 or 1
    const int i   = rem & 4095;
    const int lane = threadIdx.x & 63;
    const int w    = threadIdx.x >> 6;  // wave 0..3
    const int h    = hg * 4 + w;
    const int g    = lane & 7;          // dim-chunk within edge
    const int grp  = lane >> 3;         // edge slot 0..7
    const size_t rowbase = ((size_t)(n * L + i)) * CH + h * DD;

    // Q fragment, pre-scaled by 1/sqrt(64) * log2(e)
    constexpr float SCALE = 0.125f * 1.44269504088896f;
    f32x2 qf[4];
    {
        const short8 qu = *(const short8*)(qb + rowbase + g * 8);
        const unsigned int* qw = (const unsigned int*)&qu;
#pragma unroll
        for (int e = 0; e < 4; e++) {
            qf[e].x = u2f(qw[e] << 16) * SCALE;
            qf[e].y = u2f(qw[e] & 0xffff0000u) * SCALE;
        }
    }
    const int start = rowptr[i], end = rowptr[i + 1];
    const char* kb_nh = (const char*)(kb + (size_t)n * L * CH + h * DD);
    const char* vb_nh = (const char*)(vb + (size_t)n * L * CH + h * DD);

    f32x2 o2[4] = {};
    float lsum = 0.f;

    const int nIter = (end - start + 7) >> 3;
    int idx = start + grp;
    int j = (nIter > 0) ? ecol[min(idx, end - 1)] : 0;
    for (int it = 0; it < nIter; ++it) {
        const bool valid = idx < end;
        const int off = (j << 10) + (g << 4);
        const short8 ku = *(const short8*)(kb_nh + off);
        const short8 vu = *(const short8*)(vb_nh + off);
        // prefetch next iteration's column index (hides ecol->K dependency)
        const int idxn = idx + 8;
        const int jn = ecol[min(idxn, end - 1)];
        const unsigned int* kw = (const unsigned int*)&ku;
        f32x2 s2 = {0.f, 0.f};
#pragma unroll
        for (int e = 0; e < 4; e++) {
            f32x2 k2;
            k2.x = u2f(kw[e] << 16);
            k2.y = u2f(kw[e] & 0xffff0000u);
            s2 += k2 * qf[e];              // v_pk_fma_f32
        }
        float s = s2.x + s2.y;
        s += __shfl_xor(s, 1);
        s += __shfl_xor(s, 2);
        s += __shfl_xor(s, 4);
        float pe = exp2f(s);
        pe = valid ? pe : 0.f;
        const unsigned int* vw = (const unsigned int*)&vu;
        const f32x2 pe2 = {pe, pe};
#pragma unroll
        for (int e = 0; e < 4; e++) {
            f32x2 v2;
            v2.x = u2f(vw[e] << 16);
            v2.y = u2f(vw[e] & 0xffff0000u);
            o2[e] += pe2 * v2;             // v_pk_fma_f32
        }
        lsum += pe;
        idx = idxn;
        j = jn;
    }

    // total lsum across the 8 groups (lsum is uniform within a group)
    lsum += __shfl_xor(lsum, 8);
    lsum += __shfl_xor(lsum, 16);
    lsum += __shfl_xor(lsum, 32);

    // merge o across groups via per-wave LDS transpose
    float* p = part + w * (8 * 68);
    float* pw = p + grp * 68 + g * 8;
    *(f32x4*)(pw)     = f32x4{o2[0].x, o2[0].y, o2[1].x, o2[1].y};
    *(f32x4*)(pw + 4) = f32x4{o2[2].x, o2[2].y, o2[3].x, o2[3].y};
    __builtin_amdgcn_s_waitcnt(0);  // lgkm drain (same-wave LDS RAW)
    float osum = 0.f;
#pragma unroll
    for (int gg = 0; gg < 8; gg++)
        osum += p[gg * 68 + lane];

    const float inv = (end > start) ? 1.f / lsum : 0.f;
    agg[rowbase + lane] = f2bf(osum * inv);
}

extern "C" void kernel_launch(void* const* d_in, const int* in_sizes, int n_in,
                              void* d_out, int out_size, void* d_ws, size_t ws_size,
                              hipStream_t stream)
{
    (void)in_sizes; (void)n_in; (void)out_size; (void)ws_size;
    const float* queries = (const float*)d_in[0];
    const float* keys    = (const float*)d_in[1];
    const float* values  = (const float*)d_in[2];
    const int*   adj     = (const int*)d_in[3];
    const float* Wq  = (const float*)d_in[4];
    const float* bq  = (const float*)d_in[5];
    const float* Wk  = (const float*)d_in[6];
    const float* bk  = (const float*)d_in[7];
    const float* Wv  = (const float*)d_in[8];
    const float* bv  = (const float*)d_in[9];
    const float* Wfc = (const float*)d_in[10];
    const float* bfc = (const float*)d_in[11];

    // q/k bf16 projections live inside d_out (dead before final GEMM writes it)
    unsigned short* qb = (unsigned short*)d_out;               // 33.5 MB
    unsigned short* kb = qb + (size_t)M_ROWS * CH;             // 33.5 MB
    uint8_t* w = (uint8_t*)d_ws;
    unsigned short* vb  = (unsigned short*)(w);                          // 33.5 MB
    unsigned short* agg = (unsigned short*)(w + 33554432);               // 33.5 MB
    unsigned short* wbf = (unsigned short*)(w + 67108864);               // 2 MB (4 weights)
    int* cnt    = (int*)(w + 69206016);
    int* fill   = (int*)(w + 69206016 + 16384);
    int* rowptr = (int*)(w + 69206016 + 32768);
    int* ecol   = (int*)(w + 69206016 + 65536);                          // 512 KB

    constexpr int WELEM = CH * CH;  // 262144

    cvtw_k<<<dim3(WELEM / (256 * 8), 4), 256, 0, stream>>>(Wq, Wk, Wv, Wfc, wbf);

    dim3 gg(1024);  // (M/128)*(N/128) = 256*4
    gemm_bf<true, false><<<gg, 256, 0, stream>>>(queries, wbf + 0 * WELEM, bq, qb);
    gemm_bf<true, false><<<gg, 256, 0, stream>>>(keys,    wbf + 1 * WELEM, bk, kb);
    gemm_bf<true, false><<<gg, 256, 0, stream>>>(values,  wbf + 2 * WELEM, bv, vb);

    zero_k<<<(L + 255) / 256, 256, 0, stream>>>(cnt, fill);
    count_k<<<(NE + 255) / 256, 256, 0, stream>>>(adj, cnt);
    scan_k<<<1, 64, 0, stream>>>(cnt, rowptr);
    scatter_k<<<(NE + 255) / 256, 256, 0, stream>>>(adj, rowptr, fill, ecol);

    attn_k<<<dim3(2 * NB * L), 256, 0, stream>>>(qb, kb, vb, rowptr, ecol, agg);
    // grid = 2(hg) * 8(n) * 4096(i) = 65536 blocks

    gemm_bf<false, true><<<gg, 256, 0, stream>>>(agg, wbf + 3 * WELEM, bfc, (float*)d_out);
}

// Round 5
// 391.442 us; speedup vs baseline: 1.0350x; 1.0350x over previous
//
#include <hip/hip_runtime.h>
#include <cstdint>

typedef __attribute__((ext_vector_type(8))) short short8;
typedef __attribute__((ext_vector_type(4))) float f32x4;

#define AS1 __attribute__((address_space(1)))
#define AS3 __attribute__((address_space(3)))

constexpr int NB   = 8;
constexpr int L    = 4096;
constexpr int CH   = 512;     // model dim == E_IN
constexpr int DD   = 64;
constexpr int NE   = 131072;
constexpr int M_ROWS = NB * L;  // 32768

__device__ __forceinline__ unsigned short f2bf(float f) {
    unsigned int x; __builtin_memcpy(&x, &f, 4);
    x += 0x7fffu + ((x >> 16) & 1u);
    return (unsigned short)(x >> 16);
}
__device__ __forceinline__ float u2f(unsigned int x) {
    float f; __builtin_memcpy(&f, &x, 4); return f;
}
// 2x f32 -> packed bf16 dword (lo=a, hi=b), single HW instr (verified gfx950)
__device__ __forceinline__ unsigned int cvt_pk_bf16(float a, float b) {
    unsigned int r;
    asm("v_cvt_pk_bf16_f32 %0, %1, %2" : "=v"(r) : "v"(a), "v"(b));
    return r;
}
__device__ __forceinline__ float f2i(int x) { float f; __builtin_memcpy(&f, &x, 4); return f; }
__device__ __forceinline__ int i2f(float x) { int i; __builtin_memcpy(&i, &x, 4); return i; }
// add lane-swapped value via DPP (no DS pipe): ctrl 0xB1 = xor1, 0x4E = xor2
template <int CTRL>
__device__ __forceinline__ float dpp_add(float s) {
    int t = __builtin_amdgcn_update_dpp(0, i2f(s), CTRL, 0xF, 0xF, true);
    return s + f2i(t);
}

// ---------------- f32 -> bf16 weight convert (2 MB total, tiny) ----------------
__global__ __launch_bounds__(256)
void cvtw_k(const float* __restrict__ s0, const float* __restrict__ s1,
            const float* __restrict__ s2, const float* __restrict__ s3,
            unsigned short* __restrict__ dst) {
    const float* s = (blockIdx.y == 0) ? s0 : (blockIdx.y == 1) ? s1
                   : (blockIdx.y == 2) ? s2 : s3;
    unsigned short* d = dst + (size_t)blockIdx.y * (CH * CH);
    const int i = blockIdx.x * 256 + threadIdx.x;
    const float4 a = ((const float4*)s)[i * 2];
    const float4 b = ((const float4*)s)[i * 2 + 1];
    unsigned short us[8];
    us[0] = f2bf(a.x); us[1] = f2bf(a.y); us[2] = f2bf(a.z); us[3] = f2bf(a.w);
    us[4] = f2bf(b.x); us[5] = f2bf(b.y); us[6] = f2bf(b.z); us[7] = f2bf(b.w);
    ((short8*)d)[i] = *(short8*)us;
}

// ---------------- B^T GEMM: C[m][n] = sum_k A[m][k]*B[n][k] + bias[n]
// M=32768, N=512, K=512. 128x128 tile, BK=64, 256 thr (4 waves 2x2).
// A_F32: A staged as raw f32 via global_load_lds (async pipe kept), converted
//        to bf16 with v_cvt_pk_bf16_f32 AFTER ds_read -> no separate cvt pass.
// else:  A bf16 via global_load_lds width-16.  B always bf16 via global_load_lds.
// XCD-swizzled block id (4 consecutive blocks on one XCD share the A row-panel).
template <bool A_F32, bool OUT_F32>
__global__ __launch_bounds__(256)
void gemm_bf(const void* __restrict__ Ap, const unsigned short* __restrict__ B,
             const float* __restrict__ bias, void* __restrict__ Cp)
{
    constexpr int ABYTES = A_F32 ? 128 * 64 * 4 : 128 * 64 * 2;
    __shared__ __align__(16) char AsRaw[ABYTES];
    __shared__ unsigned short Bs[128 * 64];
    const int bid = blockIdx.x;                     // 1024 blocks
    const int swz = (bid & 7) * 128 + (bid >> 3);   // bijective XCD swizzle
    const int row0 = (swz >> 2) * 128;
    const int col0 = (swz & 3) * 128;
    const int t = threadIdx.x, lane = t & 63, wid = t >> 6;
    const int wm = (wid >> 1) * 64, wn = (wid & 1) * 64;
    const int fr = lane & 15, fkb = (lane >> 4) * 8;
    const int srow = lane >> 3;          // bf16 staging: row within 8-row chunk
    const int scol = (lane & 7) * 8;     // bf16 staging: k-elem offset
    const int srow4 = lane >> 4;         // f32 staging: row within 4-row chunk
    const int scol4 = (lane & 15) * 4;   // f32 staging: k-elem offset

    f32x4 acc[4][4] = {};

    for (int k0 = 0; k0 < CH; k0 += 64) {
        if constexpr (A_F32) {
            float* Af = (float*)AsRaw;
#pragma unroll
            for (int q = 0; q < 8; q++) {
                const int r = wid * 32 + q * 4;
                __builtin_amdgcn_global_load_lds(
                    (const AS1 unsigned int*)
                        ((const float*)Ap + (size_t)(row0 + r + srow4) * CH + k0 + scol4),
                    (AS3 unsigned int*)(Af + r * 64), 16, 0, 0);
            }
        } else {
#pragma unroll
            for (int q = 0; q < 4; q++) {
                const int r = wid * 32 + q * 8;
                __builtin_amdgcn_global_load_lds(
                    (const AS1 unsigned int*)
                        ((const unsigned short*)Ap + (size_t)(row0 + r + srow) * CH + k0 + scol),
                    (AS3 unsigned int*)((unsigned short*)AsRaw + r * 64), 16, 0, 0);
            }
        }
#pragma unroll
        for (int q = 0; q < 4; q++) {
            const int r = wid * 32 + q * 8;
            __builtin_amdgcn_global_load_lds(
                (const AS1 unsigned int*)
                    (B + (size_t)(col0 + r + srow) * CH + k0 + scol),
                (AS3 unsigned int*)(Bs + r * 64), 16, 0, 0);
        }
        __syncthreads();
#pragma unroll
        for (int kk = 0; kk < 2; kk++) {
            short8 afr[4], bfr[4];
            if constexpr (A_F32) {
                const float* Af = (const float*)AsRaw;
#pragma unroll
                for (int f = 0; f < 4; f++) {
                    const float4 x0 = *(const float4*)&Af[(wm + f * 16 + fr) * 64 + kk * 32 + fkb];
                    const float4 x1 = *(const float4*)&Af[(wm + f * 16 + fr) * 64 + kk * 32 + fkb + 4];
                    unsigned int pk[4];
                    pk[0] = cvt_pk_bf16(x0.x, x0.y);
                    pk[1] = cvt_pk_bf16(x0.z, x0.w);
                    pk[2] = cvt_pk_bf16(x1.x, x1.y);
                    pk[3] = cvt_pk_bf16(x1.z, x1.w);
                    afr[f] = *(short8*)pk;
                }
            } else {
#pragma unroll
                for (int f = 0; f < 4; f++)
                    afr[f] = *(const short8*)&((const unsigned short*)AsRaw)
                        [(wm + f * 16 + fr) * 64 + kk * 32 + fkb];
            }
#pragma unroll
            for (int f = 0; f < 4; f++)
                bfr[f] = *(const short8*)&Bs[(wn + f * 16 + fr) * 64 + kk * 32 + fkb];
#pragma unroll
            for (int fm = 0; fm < 4; fm++)
#pragma unroll
                for (int fn = 0; fn < 4; fn++)
                    acc[fm][fn] = __builtin_amdgcn_mfma_f32_16x16x32_bf16(
                        afr[fm], bfr[fn], acc[fm][fn], 0, 0, 0);
        }
        __syncthreads();
    }

    const int rsub = (lane >> 4) * 4;
#pragma unroll
    for (int fn = 0; fn < 4; fn++) {
        const int gc = col0 + wn + fn * 16 + fr;
        const float bv = bias[gc];
#pragma unroll
        for (int fm = 0; fm < 4; fm++) {
            const int gr = row0 + wm + fm * 16 + rsub;
#pragma unroll
            for (int j = 0; j < 4; j++) {
                float v = acc[fm][fn][j] + bv;
                if constexpr (OUT_F32)
                    ((float*)Cp)[(size_t)(gr + j) * CH + gc] = v;
                else
                    ((unsigned short*)Cp)[(size_t)(gr + j) * CH + gc] = f2bf(v);
            }
        }
    }
}

// ---------------- CSR build ----------------
__global__ void zero_k(int* cnt, int* fill) {
    int i = blockIdx.x * blockDim.x + threadIdx.x;
    if (i < L) { cnt[i] = 0; fill[i] = 0; }
}
__global__ void count_k(const int* __restrict__ adj, int* __restrict__ cnt) {
    int e = blockIdx.x * blockDim.x + threadIdx.x;
    if (e < NE) atomicAdd(&cnt[adj[e]], 1);
}
__global__ void scan_k(const int* __restrict__ cnt, int* __restrict__ rowptr) {
    const int lane = threadIdx.x;      // 64 threads, 1 wave
    const int base = lane * 64;
    int s = 0;
    for (int t2 = 0; t2 < 64; t2++) s += cnt[base + t2];
    int incl = s;
    for (int off = 1; off < 64; off <<= 1) {
        int v = __shfl_up(incl, off);
        if (lane >= off) incl += v;
    }
    int run = incl - s;   // exclusive prefix
    for (int t2 = 0; t2 < 64; t2++) { rowptr[base + t2] = run; run += cnt[base + t2]; }
    if (lane == 63) rowptr[L] = run;
}
__global__ void scatter_k(const int* __restrict__ adj, const int* __restrict__ rowptr,
                          int* __restrict__ fill, int* __restrict__ ecol) {
    int e = blockIdx.x * blockDim.x + threadIdx.x;
    if (e < NE) {
        int rr = adj[e];
        int pos = rowptr[rr] + atomicAdd(&fill[rr], 1);
        ecol[pos] = adj[NE + e];
    }
}

// ---------------- fused edge-softmax + SPMM ----------------
// block = (i, n, hg): 256 threads = 4 waves, wave w handles head hg*4+w.
// XCD pinning: n = bid & 7 -> per-XCD live K/V slice = 4 MB = one L2.
// Wave: 16 groups x 4 lanes; each group owns one edge/iter, lane g holds
// dims g*16..g*16+15 (2x 16B loads). Intra-group dot-reduce via DPP adds
// (quad_perm xor1/xor2) - no DS-pipe ops in the hot loop.
// No-max softmax (scores ~N(0,1); exp2-domain, scale folded into Q).
__global__ __launch_bounds__(256)
void attn_k(const unsigned short* __restrict__ qb, const unsigned short* __restrict__ kb,
            const unsigned short* __restrict__ vb, const int* __restrict__ rowptr,
            const int* __restrict__ ecol, unsigned short* __restrict__ agg)
{
    __shared__ float part[4 * 16 * 68];   // [wave][grp][68]
    const int bid = blockIdx.x;
    const int n   = bid & 7;
    const int rem = bid >> 3;
    const int hg  = rem >> 12;          // 0 or 1
    const int i   = rem & 4095;
    const int lane = threadIdx.x & 63;
    const int w    = threadIdx.x >> 6;  // wave 0..3
    const int h    = hg * 4 + w;
    const int g    = lane & 3;          // dim-chunk (16 elems) within edge
    const int grp  = lane >> 2;         // edge slot 0..15
    const size_t rowbase = ((size_t)(n * L + i)) * CH + h * DD;

    // Q fragment (16 dims), pre-scaled by 1/sqrt(64) * log2(e)
    constexpr float SCALE = 0.125f * 1.44269504088896f;
    float qf[16];
    {
        const short8 qu0 = *(const short8*)(qb + rowbase + g * 16);
        const short8 qu1 = *(const short8*)(qb + rowbase + g * 16 + 8);
        const unsigned int* qw0 = (const unsigned int*)&qu0;
        const unsigned int* qw1 = (const unsigned int*)&qu1;
#pragma unroll
        for (int e = 0; e < 4; e++) {
            qf[2 * e]     = u2f(qw0[e] << 16) * SCALE;
            qf[2 * e + 1] = u2f(qw0[e] & 0xffff0000u) * SCALE;
            qf[8 + 2 * e]     = u2f(qw1[e] << 16) * SCALE;
            qf[8 + 2 * e + 1] = u2f(qw1[e] & 0xffff0000u) * SCALE;
        }
    }
    const int start = rowptr[i], end = rowptr[i + 1];
    const char* kb_nh = (const char*)(kb + (size_t)n * L * CH + h * DD);
    const char* vb_nh = (const char*)(vb + (size_t)n * L * CH + h * DD);

    float o[16] = {};
    float lsum = 0.f;

    const int nIter = (end - start + 15) >> 4;
    int idx = start + grp;
    int j = (nIter > 0) ? ecol[min(idx, end - 1)] : 0;
    for (int it = 0; it < nIter; ++it) {
        const bool valid = idx < end;
        const int off = (j << 10) + (g << 5);
        const short8 ku0 = *(const short8*)(kb_nh + off);
        const short8 ku1 = *(const short8*)(kb_nh + off + 16);
        const short8 vu0 = *(const short8*)(vb_nh + off);
        const short8 vu1 = *(const short8*)(vb_nh + off + 16);
        // prefetch next iteration's column index (hides ecol->K dependency)
        const int idxn = idx + 16;
        const int jn = ecol[min(idxn, end - 1)];
        const unsigned int* kw0 = (const unsigned int*)&ku0;
        const unsigned int* kw1 = (const unsigned int*)&ku1;
        float s = 0.f;
#pragma unroll
        for (int e = 0; e < 4; e++) {
            s = fmaf(u2f(kw0[e] << 16),         qf[2 * e],     s);
            s = fmaf(u2f(kw0[e] & 0xffff0000u), qf[2 * e + 1], s);
            s = fmaf(u2f(kw1[e] << 16),         qf[8 + 2 * e],     s);
            s = fmaf(u2f(kw1[e] & 0xffff0000u), qf[8 + 2 * e + 1], s);
        }
        s = dpp_add<0xB1>(s);   // + lane^1 (quad_perm [1,0,3,2])
        s = dpp_add<0x4E>(s);   // + lane^2 (quad_perm [2,3,0,1])
        float pe = exp2f(s);
        pe = valid ? pe : 0.f;
        const unsigned int* vw0 = (const unsigned int*)&vu0;
        const unsigned int* vw1 = (const unsigned int*)&vu1;
#pragma unroll
        for (int e = 0; e < 4; e++) {
            o[2 * e]     = fmaf(pe, u2f(vw0[e] << 16),         o[2 * e]);
            o[2 * e + 1] = fmaf(pe, u2f(vw0[e] & 0xffff0000u), o[2 * e + 1]);
            o[8 + 2 * e]     = fmaf(pe, u2f(vw1[e] << 16),         o[8 + 2 * e]);
            o[8 + 2 * e + 1] = fmaf(pe, u2f(vw1[e] & 0xffff0000u), o[8 + 2 * e + 1]);
        }
        lsum += pe;
        idx = idxn;
        j = jn;
    }

    // total lsum across the 16 groups (uniform within each 4-lane group)
    lsum += __shfl_xor(lsum, 4);
    lsum += __shfl_xor(lsum, 8);
    lsum += __shfl_xor(lsum, 16);
    lsum += __shfl_xor(lsum, 32);

    // merge o across groups via per-wave LDS transpose
    float* p = part + w * (16 * 68);
    float* pw = p + grp * 68 + g * 16;
#pragma unroll
    for (int q = 0; q < 4; q++)
        *(f32x4*)(pw + q * 4) = *(f32x4*)&o[q * 4];
    __builtin_amdgcn_s_waitcnt(0);  // lgkm drain (same-wave LDS RAW)
    float osum = 0.f;
#pragma unroll
    for (int gg = 0; gg < 16; gg++)
        osum += p[gg * 68 + lane];

    const float inv = (end > start) ? 1.f / lsum : 0.f;
    agg[rowbase + lane] = f2bf(osum * inv);
}

extern "C" void kernel_launch(void* const* d_in, const int* in_sizes, int n_in,
                              void* d_out, int out_size, void* d_ws, size_t ws_size,
                              hipStream_t stream)
{
    (void)in_sizes; (void)n_in; (void)out_size; (void)ws_size;
    const float* queries = (const float*)d_in[0];
    const float* keys    = (const float*)d_in[1];
    const float* values  = (const float*)d_in[2];
    const int*   adj     = (const int*)d_in[3];
    const float* Wq  = (const float*)d_in[4];
    const float* bq  = (const float*)d_in[5];
    const float* Wk  = (const float*)d_in[6];
    const float* bk  = (const float*)d_in[7];
    const float* Wv  = (const float*)d_in[8];
    const float* bv  = (const float*)d_in[9];
    const float* Wfc = (const float*)d_in[10];
    const float* bfc = (const float*)d_in[11];

    // q/k bf16 projections live inside d_out (dead before final GEMM writes it)
    unsigned short* qb = (unsigned short*)d_out;               // 33.5 MB
    unsigned short* kb = qb + (size_t)M_ROWS * CH;             // 33.5 MB
    uint8_t* w = (uint8_t*)d_ws;
    unsigned short* vb  = (unsigned short*)(w);                          // 33.5 MB
    unsigned short* agg = (unsigned short*)(w + 33554432);               // 33.5 MB
    unsigned short* wbf = (unsigned short*)(w + 67108864);               // 2 MB (4 weights)
    int* cnt    = (int*)(w + 69206016);
    int* fill   = (int*)(w + 69206016 + 16384);
    int* rowptr = (int*)(w + 69206016 + 32768);
    int* ecol   = (int*)(w + 69206016 + 65536);                          // 512 KB

    constexpr int WELEM = CH * CH;  // 262144

    cvtw_k<<<dim3(WELEM / (256 * 8), 4), 256, 0, stream>>>(Wq, Wk, Wv, Wfc, wbf);

    dim3 gg(1024);  // (M/128)*(N/128) = 256*4
    gemm_bf<true, false><<<gg, 256, 0, stream>>>(queries, wbf + 0 * WELEM, bq, qb);
    gemm_bf<true, false><<<gg, 256, 0, stream>>>(keys,    wbf + 1 * WELEM, bk, kb);
    gemm_bf<true, false><<<gg, 256, 0, stream>>>(values,  wbf + 2 * WELEM, bv, vb);

    zero_k<<<(L + 255) / 256, 256, 0, stream>>>(cnt, fill);
    count_k<<<(NE + 255) / 256, 256, 0, stream>>>(adj, cnt);
    scan_k<<<1, 64, 0, stream>>>(cnt, rowptr);
    scatter_k<<<(NE + 255) / 256, 256, 0, stream>>>(adj, rowptr, fill, ecol);

    attn_k<<<dim3(2 * NB * L), 256, 0, stream>>>(qb, kb, vb, rowptr, ecol, agg);
    // grid = 2(hg) * 8(n) * 4096(i) = 65536 blocks

    gemm_bf<false, true><<<gg, 256, 0, stream>>>(agg, wbf + 3 * WELEM, bfc, (float*)d_out);
}